// Round 15
// baseline (59.352 us; speedup 1.0000x reference)
//
#include <hip/hip_runtime.h>
#include <hip/hip_cooperative_groups.h>

// ---------------------------------------------------------------------------
// CausalFullAttention (decay-gated causal linear attention), MI355X gfx950
// b=2, n=2048, DIM=512, HEADS=8, DIM_HEAD=64
// R15: == R14, but 3 of 4 grid.syncs replaced by per-group flag sync
//      (device-scope atomics; coop launch => co-resident => no deadlock):
//      S2->S3 per-bh (32 posts), S3->S45 per-bh (posted right after Sbuf
//      store), S45->S6 per-(b,chunk) (8 posts). One grid.sync remains
//      (after S1, also publishes flag zeroing).
//      Fallback = R12's proven 6-kernel path (unchanged, no flags).
// ---------------------------------------------------------------------------

namespace cg = cooperative_groups;

using s8v   = __attribute__((ext_vector_type(8))) short;   // 8 x bf16 bits
using f32x4 = __attribute__((ext_vector_type(4))) float;

__device__ __forceinline__ unsigned short f2b(float f) {
  unsigned int u = __builtin_bit_cast(unsigned int, f);
  u += 0x7FFFu + ((u >> 16) & 1u);          // RNE
  return (unsigned short)(u >> 16);
}
__device__ __forceinline__ float b2f(unsigned short b) {
  unsigned int u = ((unsigned int)b) << 16;
  return __builtin_bit_cast(float, u);
}
__device__ __forceinline__ f32x4 mfma16(s8v a, s8v b, f32x4 c) {
  return __builtin_amdgcn_mfma_f32_16x16x32_bf16(a, b, c, 0, 0, 0);
}
__device__ __forceinline__ void gload16(const void* g, void* l) {
  __builtin_amdgcn_global_load_lds(
      (const __attribute__((address_space(1))) void*)g,
      (__attribute__((address_space(3))) void*)l, 16, 0, 0);
}

// ---- producer/consumer flag sync (device scope) ----------------------------
__device__ __forceinline__ void post_flag(int* f) {
  __threadfence();                         // all threads: publish data writes
  __syncthreads();                         // everyone's writes+fence done
  if (threadIdx.x == 0)
    __hip_atomic_fetch_add(f, 1, __ATOMIC_RELEASE, __HIP_MEMORY_SCOPE_AGENT);
}
__device__ __forceinline__ void wait_flag(int* f, int target) {
  if (threadIdx.x == 0) {
    while (__hip_atomic_load(f, __ATOMIC_ACQUIRE, __HIP_MEMORY_SCOPE_AGENT) < target)
      __builtin_amdgcn_s_sleep(2);
  }
  __syncthreads();
}

// ---------------- stage: prep (rmsnorm u<1024 | wtrans u>=1024) --------------
__device__ __forceinline__ void st_prep(int u, int tid, char* arena,
    const float* __restrict__ x, const float* __restrict__ gamma,
    short* __restrict__ xnb,
    const float* __restrict__ w_qkv, const float* __restrict__ w_a,
    const float* __restrict__ w_out,
    short* __restrict__ wT, short* __restrict__ woT) {
  int lane = tid & 63, wave = tid >> 6;
  if (u < 1024) {
    int row = u * 4 + wave;
    const float4* xp = reinterpret_cast<const float4*>(x + (size_t)row * 512 + lane * 8);
    float4 v0 = xp[0], v1 = xp[1];
    float ss = v0.x*v0.x + v0.y*v0.y + v0.z*v0.z + v0.w*v0.w
             + v1.x*v1.x + v1.y*v1.y + v1.z*v1.z + v1.w*v1.w;
#pragma unroll
    for (int off = 32; off > 0; off >>= 1) ss += __shfl_xor(ss, off, 64);
    float s = 22.627416997969522f / fmaxf(sqrtf(ss), 1e-12f);
    const float* g = gamma + lane * 8;
    float vals[8] = {v0.x, v0.y, v0.z, v0.w, v1.x, v1.y, v1.z, v1.w};
    s8v o;
#pragma unroll
    for (int j = 0; j < 8; ++j) o[j] = (short)f2b(vals[j] * s * g[j]);
    *reinterpret_cast<s8v*>(xnb + (size_t)row * 512 + lane * 8) = o;
  } else {
    float (*t)[33] = reinterpret_cast<float (*)[33]>(arena);
    int id = u - 1024;
    int bx = id % 80, k0 = (id / 80) * 32;
    const float* src; short* dst; int N, n0;
    if (bx < 48)      { src = w_qkv; dst = wT;                      N = 1536; n0 = bx * 32; }
    else if (bx < 64) { src = w_a;   dst = wT + (size_t)1536 * 512; N = 512;  n0 = (bx - 48) * 32; }
    else              { src = w_out; dst = woT;                     N = 512;  n0 = (bx - 64) * 32; }
    int tx = tid & 31, ty = tid >> 5;
    __syncthreads();   // prior arena use complete
#pragma unroll
    for (int i = 0; i < 4; ++i)
      t[ty + 8 * i][tx] = src[(size_t)(k0 + ty + 8 * i) * N + n0 + tx];
    __syncthreads();
#pragma unroll
    for (int i = 0; i < 4; ++i)
      dst[(size_t)(n0 + ty + 8 * i) * 512 + k0 + tx] = (short)f2b(t[tx][ty + 8 * i]);
  }
}

// ---------------- single-buffered GEMM core (m97 structure), WRxWC waves -----
template <int BM, int BN, int WR, int WC>
__device__ __forceinline__ void gemm_core(const short* __restrict__ A,
                                          const short* __restrict__ Bm,
                                          char* LA, char* LB,
                                          int m0, int n0, int tid,
                                          f32x4 (&acc)[BM / WR / 16][BN / WC / 16]) {
  constexpr int WM = BM / WR, WN = BN / WC, FM = WM / 16, FN = WN / 16;
  const int lane = tid & 63, wave = tid >> 6;
  const int wr = (wave / WC) * WM, wc = (wave % WC) * WN;
#pragma unroll 1
  for (int t = 0; t < 8; ++t) {            // K = 512, BK = 64
    const int k0 = t * 64;
#pragma unroll
    for (int r = 0; r < BM / 32; ++r) {
      int o = r * 4096 + tid * 16;
      int row = o >> 7;
      int ce = (((o & 127) ^ ((row & 7) << 4)) >> 1);   // pre-swizzled src col
      gload16(A + (size_t)(m0 + row) * 512 + k0 + ce, LA + o);
    }
#pragma unroll
    for (int r = 0; r < BN / 32; ++r) {
      int o = r * 4096 + tid * 16;
      int row = o >> 7;
      int ce = (((o & 127) ^ ((row & 7) << 4)) >> 1);
      gload16(Bm + (size_t)(n0 + row) * 512 + k0 + ce, LB + o);
    }
    __syncthreads();                       // tile ready (vmcnt drained)
#pragma unroll
    for (int kk = 0; kk < 2; ++kk) {
      s8v af[FM], bf[FN];
#pragma unroll
      for (int m = 0; m < FM; ++m) {
        int row = wr + m * 16 + (lane & 15);
        int ad = ((row << 7) + kk * 64 + ((lane >> 4) << 4)) ^ ((row & 7) << 4);
        af[m] = *reinterpret_cast<const s8v*>(LA + ad);
      }
#pragma unroll
      for (int n = 0; n < FN; ++n) {
        int row = wc + n * 16 + (lane & 15);
        int ad = ((row << 7) + kk * 64 + ((lane >> 4) << 4)) ^ ((row & 7) << 4);
        bf[n] = *reinterpret_cast<const s8v*>(LB + ad);
      }
#pragma unroll
      for (int m = 0; m < FM; ++m)
#pragma unroll
        for (int n = 0; n < FN; ++n)
          acc[m][n] = mfma16(af[m], bf[n], acc[m][n]);
    }
    if (t + 1 < 8) __syncthreads();        // reads done before next overwrite
  }
}

// chunk-prefix over csum with fixed-32 unroll (independent loads, masked add)
__device__ __forceinline__ float csum_prefix(const float* __restrict__ csum,
                                             int bh, int chunk, int d) {
  float pre = 0.f;
#pragma unroll
  for (int c = 0; c < 32; ++c) {
    float cv = csum[((size_t)bh * 32 + c) * 64 + d];
    pre += (c < chunk) ? cv : 0.f;
  }
  return pre;
}

// ================== FALLBACK stages (R12 path, proven) =======================
__device__ __forceinline__ void st_gemm0_fb(int vid, int tid, char* arena,
    const short* __restrict__ xnb, const short* __restrict__ wT,
    short* __restrict__ qkvb, const float* __restrict__ b_qkv,
    const float* __restrict__ b_a, float* __restrict__ araw,
    float* __restrict__ csum) {
  const int lane = tid & 63, wave = tid >> 6;
  int xcd = vid & 7, rq = vid >> 3;
  int bx = rq & 31, by = xcd * 4 + (rq >> 5);
  int m0 = by * 128, n0 = bx * 64;
  f32x4 acc[2][4] = {};
  gemm_core<128, 64, 4, 1>(xnb, wT, arena, arena + 16384, m0, n0, tid, acc);
  int wr = wave * 32;
  if (n0 < 1536) {
#pragma unroll
    for (int m = 0; m < 2; ++m)
#pragma unroll
      for (int n = 0; n < 4; ++n)
#pragma unroll
        for (int r = 0; r < 4; ++r) {
          int row = m0 + wr + m * 16 + ((lane >> 4) << 2) + r;
          int col = n0 + n * 16 + (lane & 15);
          float v = acc[m][n][r] + b_qkv[col];
          int w = col >> 9, h = (col >> 6) & 7, d = col & 63;
          int b = row >> 11, nn = row & 2047;
          qkvb[((((size_t)(w * 2 + b)) * 8 + h) * 2048 + nn) * 64 + d] = (short)f2b(v);
        }
  } else {
    __syncthreads();
    float (*WSUM)[64] = reinterpret_cast<float (*)[64]>(arena);
    float cs[4] = {};
    int b = m0 >> 11;
#pragma unroll
    for (int m = 0; m < 2; ++m)
#pragma unroll
      for (int n = 0; n < 4; ++n)
#pragma unroll
        for (int r = 0; r < 4; ++r) {
          int row = m0 + wr + m * 16 + ((lane >> 4) << 2) + r;
          int gc = n0 + n * 16 + (lane & 15) - 1536;
          int h = gc >> 6, d = gc & 63, nn = row & 2047;
          float xv = acc[m][n][r] + b_a[gc];
          araw[((size_t)(b * 8 + h) * 2048 + nn) * 64 + d] = xv;
          float a = 1.f / (1.f + expf(-xv));
          a = fminf(fmaxf(a, 1e-10f), 1.f);
          cs[n] += logf(a);
        }
#pragma unroll
    for (int n = 0; n < 4; ++n) {
      cs[n] += __shfl_xor(cs[n], 16, 64);
      cs[n] += __shfl_xor(cs[n], 32, 64);
    }
    if (lane < 16) {
#pragma unroll
      for (int n = 0; n < 4; ++n) WSUM[wave][n * 16 + lane] = cs[n];
    }
    __syncthreads();
    if (tid < 128) {
      int cl = tid >> 6, col = tid & 63;
      float s = WSUM[2 * cl][col] + WSUM[2 * cl + 1][col];
      int h = (n0 - 1536) >> 6;
      int chunkg = ((m0 & 2047) >> 6) + cl;
      csum[(((size_t)(b * 8 + h)) * 32 + chunkg) * 64 + col] = s;
    }
  }
}

__device__ __forceinline__ void st_scan2(int vid, int tid, char* arena,
    const short* __restrict__ qkvb, const float* __restrict__ araw,
    const float* __restrict__ csum, short* __restrict__ q2,
    short* __restrict__ k2, short* __restrict__ vT, short* __restrict__ Sbuf) {
  int chunk = vid & 31, bh = vid >> 5;
  int lane = tid & 63, wave = tid >> 6, d = lane;
  short (*kL)[64] = reinterpret_cast<short (*)[64]>(arena);
  short (*vL)[64] = reinterpret_cast<short (*)[64]>(arena + 8192);
  char* kT  = arena + 16384;
  char* vTl = arena + 24576;
  float (*wsum)[64] = reinterpret_cast<float (*)[64]>(arena + 16384);
  float pre = csum_prefix(csum, bh, chunk, d);
  const float* ap = araw + ((size_t)bh * 2048 + chunk * 64 + wave * 16) * 64 + d;
  float la[16]; float run = 0.f;
#pragma unroll
  for (int rr = 0; rr < 16; ++rr) {
    float xv = ap[rr * 64];
    float a = 1.f / (1.f + expf(-xv));
    a = fminf(fmaxf(a, 1e-10f), 1.f);
    run += logf(a);
    la[rr] = run;
  }
  wsum[wave][d] = run;
  __syncthreads();
#pragma unroll
  for (int w = 0; w < 3; ++w) if (w < wave) pre += wsum[w][d];
  const size_t WS = (size_t)2 * 8 * 2048 * 64;
  size_t base = ((size_t)bh * 2048 + chunk * 64 + wave * 16) * 64 + d;
#pragma unroll 4
  for (int rr = 0; rr < 16; ++rr) {
    int r = wave * 16 + rr;
    float g = expf(pre + la[rr]);
    float gi = 1.f / fmaxf(g, 1e-8f);
    float qv = b2f((unsigned short)qkvb[base + rr * 64]);
    float kv = b2f((unsigned short)qkvb[base + WS + rr * 64]);
    short vb = qkvb[base + 2 * WS + rr * 64];
    q2[base + rr * 64] = (short)f2b(qv * 0.125f * g);
    unsigned short kb = f2b(kv * gi);
    k2[base + rr * 64] = (short)kb;
    kL[r][d] = (short)kb;
    vL[r][d] = vb;
  }
  __syncthreads();
  short* vTrow = vT + ((size_t)bh * 64 + d) * 2048 + chunk * 64;
#pragma unroll
  for (int gg = 0; gg < 2; ++gg) {
    int g8 = wave + gg * 4;
    s8v pk, pv;
#pragma unroll
    for (int j = 0; j < 8; ++j) { pk[j] = kL[g8 * 8 + j][d]; pv[j] = vL[g8 * 8 + j][d]; }
    *reinterpret_cast<s8v*>(vTrow + g8 * 8) = pv;
    int ad = ((d << 7) + g8 * 16) ^ ((d & 7) << 4);
    *reinterpret_cast<s8v*>(kT  + ad) = pk;
    *reinterpret_cast<s8v*>(vTl + ad) = pv;
  }
  __syncthreads();
  f32x4 acc[4] = {};
#pragma unroll
  for (int kk = 0; kk < 2; ++kk) {
    int arow = wave * 16 + (lane & 15);
    int aad = ((arow << 7) + kk * 64 + ((lane >> 4) << 4)) ^ ((arow & 7) << 4);
    s8v av = *reinterpret_cast<const s8v*>(vTl + aad);
#pragma unroll
    for (int n = 0; n < 4; ++n) {
      int brow = n * 16 + (lane & 15);
      int bad = ((brow << 7) + kk * 64 + ((lane >> 4) << 4)) ^ ((brow & 7) << 4);
      acc[n] = mfma16(av, *reinterpret_cast<const s8v*>(kT + bad), acc[n]);
    }
  }
  short* Sp = Sbuf + ((size_t)bh * 32 + chunk) * 4096;
#pragma unroll
  for (int n = 0; n < 4; ++n)
#pragma unroll
    for (int r = 0; r < 4; ++r)
      Sp[(wave * 16 + ((lane >> 4) << 2) + r) * 64 + n * 16 + (lane & 15)] = (short)f2b(acc[n][r]);
}

__device__ __forceinline__ void st_sprefix(int vid, int tid,
    const short* __restrict__ Sbuf, short* __restrict__ Spre) {
  int bh = vid >> 4;
  int e = ((vid & 15) << 8) + tid;
  size_t base = (size_t)bh * 32 * 4096 + e;
  unsigned short v[32];
#pragma unroll
  for (int c = 0; c < 32; ++c)
    v[c] = (unsigned short)Sbuf[base + (size_t)c * 4096];
  float acc = 0.f;
#pragma unroll
  for (int c = 0; c < 32; ++c) {
    Spre[base + (size_t)c * 4096] = (short)f2b(acc);
    acc += b2f(v[c]);
  }
}

__device__ __forceinline__ void st_attnk(int vid, int tid, char* arena,
    const short* __restrict__ q2, const short* __restrict__ k2,
    const short* __restrict__ vT, const short* __restrict__ Spre,
    short* __restrict__ aout) {
  int chunk = vid & 31, bh = vid >> 5;
  int lane = tid & 63, wave = tid >> 6;
  char* LQ = arena;              // later reused for P
  char* LK = arena + 8192;
  char* LV = arena + 16384;
  char* LS = arena + 24576;
#pragma unroll
  for (int rr = 0; rr < 2; ++rr) {
    int o = rr * 4096 + tid * 16;
    int row = o >> 7;
    int ce = (((o & 127) ^ ((row & 7) << 4)) >> 1);
    gload16(q2   + ((size_t)bh * 2048 + chunk * 64 + row) * 64 + ce, LQ + o);
    gload16(k2   + ((size_t)bh * 2048 + chunk * 64 + row) * 64 + ce, LK + o);
    gload16(vT   + ((size_t)bh * 64 + row) * 2048 + chunk * 64 + ce, LV + o);
    gload16(Spre + (((size_t)bh * 32 + chunk) * 64 + row) * 64 + ce, LS + o);
  }
  __syncthreads();
  f32x4 accS[4] = {}, accO[4] = {};
#pragma unroll
  for (int kk = 0; kk < 2; ++kk) {
    int arow = wave * 16 + (lane & 15);
    int aad = ((arow << 7) + kk * 64 + ((lane >> 4) << 4)) ^ ((arow & 7) << 4);
    s8v aq = *reinterpret_cast<const s8v*>(LQ + aad);
#pragma unroll
    for (int n = 0; n < 4; ++n) {
      int brow = n * 16 + (lane & 15);
      int bad = ((brow << 7) + kk * 64 + ((lane >> 4) << 4)) ^ ((brow & 7) << 4);
      accS[n] = mfma16(aq, *reinterpret_cast<const s8v*>(LK + bad), accS[n]);
      accO[n] = mfma16(aq, *reinterpret_cast<const s8v*>(LS + bad), accO[n]);
    }
  }
  __syncthreads();
#pragma unroll
  for (int n = 0; n < 4; ++n)
#pragma unroll
    for (int r = 0; r < 4; ++r) {
      int i = wave * 16 + ((lane >> 4) << 2) + r;
      int j = n * 16 + (lane & 15);
      float v = (j <= i) ? accS[n][r] : 0.f;
      int ad = ((i << 7) + (j << 1)) ^ ((i & 7) << 4);
      *reinterpret_cast<short*>(LQ + ad) = (short)f2b(v);
    }
  __syncthreads();
#pragma unroll
  for (int kk = 0; kk < 2; ++kk) {
    int arow = wave * 16 + (lane & 15);
    int aad = ((arow << 7) + kk * 64 + ((lane >> 4) << 4)) ^ ((arow & 7) << 4);
    s8v ap = *reinterpret_cast<const s8v*>(LQ + aad);
#pragma unroll
    for (int n = 0; n < 4; ++n) {
      int brow = n * 16 + (lane & 15);
      int bad = ((brow << 7) + kk * 64 + ((lane >> 4) << 4)) ^ ((brow & 7) << 4);
      accO[n] = mfma16(ap, *reinterpret_cast<const s8v*>(LV + bad), accO[n]);
    }
  }
  int b = bh >> 3, h = bh & 7;
#pragma unroll
  for (int n = 0; n < 4; ++n)
#pragma unroll
    for (int r = 0; r < 4; ++r) {
      int i = wave * 16 + ((lane >> 4) << 2) + r;
      int col = h * 64 + n * 16 + (lane & 15);
      size_t row = (size_t)b * 2048 + chunk * 64 + i;
      aout[row * 512 + col] = (short)f2b(accO[n][r]);
    }
}

__device__ __forceinline__ void st_gemm1_fb(int vid, int tid, char* arena,
    const short* __restrict__ aout, const short* __restrict__ woT,
    float* __restrict__ out, const float* __restrict__ b_out) {
  const int lane = tid & 63, wave = tid >> 6;
  int xcd = vid & 7, rq = vid >> 3;
  int bx = rq & 15, by = xcd * 8 + (rq >> 4);
  int m0 = by * 64, n0 = bx * 32;
  f32x4 acc[1][2] = {};
  gemm_core<64, 32, 4, 1>(aout, woT, arena, arena + 8192, m0, n0, tid, acc);
  int wr = wave * 16;
#pragma unroll
  for (int n = 0; n < 2; ++n)
#pragma unroll
    for (int r = 0; r < 4; ++r) {
      int row = m0 + wr + ((lane >> 4) << 2) + r;
      int col = n0 + n * 16 + (lane & 15);
      out[(size_t)row * 512 + col] = acc[0][n][r] + b_out[col];
    }
}

// ================== mega kernel (cooperative, fused, flag-synced) ============
__global__ __launch_bounds__(256, 2) void mega_k(
    const float* __restrict__ x, const float* __restrict__ gamma,
    const float* __restrict__ w_qkv, const float* __restrict__ b_qkv,
    const float* __restrict__ w_a, const float* __restrict__ b_a,
    const float* __restrict__ w_out, const float* __restrict__ b_out,
    float* __restrict__ out,
    short* __restrict__ xnb, short* __restrict__ wT, short* __restrict__ woT,
    float* __restrict__ csum, short* __restrict__ Sbuf, short* __restrict__ aout,
    int* __restrict__ flags) {
  __shared__ __align__(16) char arena[57600];
  cg::grid_group grid = cg::this_grid();
  const int bid = blockIdx.x, tid = threadIdx.x;
  const int lane = tid & 63, wave = tid >> 6;
  int* fcsum = flags;          // [16]  posts: 32 each
  int* fS    = flags + 16;     // [16]  posts: 32 each
  int* fA    = flags + 32;     // [64]  posts: 8 each

  // ---- S1: prep (2304 units over 512 blocks) + flag zeroing ----
  if (bid == 0 && tid < 96) flags[tid] = 0;
  for (int u = bid; u < 2304; u += 512)
    st_prep(u, tid, arena, x, gamma, xnb, w_qkv, w_a, w_out, wT, woT);
  __threadfence(); grid.sync();            // weights + zeroed flags visible

  // ---- unit mapping: same-bh blocks share an XCD (B-panel L2 locality) ----
  const int xcd = bid & 7, idx = bid >> 3;
  const int bh = xcd * 2 + (idx >> 5);
  const int chunk = idx & 31;
  const int b = bh >> 3, h = bh & 7;

  char* qL  = arena;
  char* kR  = arena + 8192;
  char* kT  = arena + 16384;
  char* vTl = arena + 24576;
  float* laBuf = reinterpret_cast<float*>(arena + 40960);   // [64][65]
  float (*wsumA)[64] = reinterpret_cast<float (*)[64]>(arena + 32768);
  float* preArr = reinterpret_cast<float*>(arena + 32768);

  // ---- S2a: fused 4-plane GEMM (wave w = plane w: 0=q,1=k,2=v,3=a) --------
  f32x4 acc[4][4] = {};
  {
    const int m0g = b * 2048 + chunk * 64;
    char* LBp = arena + 8192 + wave * 8192;
#pragma unroll 1
    for (int t = 0; t < 8; ++t) {
      int k0 = t * 64;
#pragma unroll
      for (int r = 0; r < 2; ++r) {
        int o = r * 4096 + tid * 16;
        int row = o >> 7;
        int ce = (((o & 127) ^ ((row & 7) << 4)) >> 1);
        gload16(xnb + (size_t)(m0g + row) * 512 + k0 + ce, arena + o);
      }
#pragma unroll
      for (int p = 0; p < 4; ++p)
#pragma unroll
        for (int r = 0; r < 2; ++r) {
          int o = r * 4096 + tid * 16;
          int row = o >> 7;
          int ce = (((o & 127) ^ ((row & 7) << 4)) >> 1);
          gload16(wT + (size_t)(p * 512 + h * 64 + row) * 512 + k0 + ce,
                  arena + 8192 + p * 8192 + o);
        }
      __syncthreads();
#pragma unroll
      for (int kk = 0; kk < 2; ++kk) {
        s8v af[4], bf[4];
#pragma unroll
        for (int m = 0; m < 4; ++m) {
          int row = m * 16 + (lane & 15);
          int ad = ((row << 7) + kk * 64 + ((lane >> 4) << 4)) ^ ((row & 7) << 4);
          af[m] = *reinterpret_cast<const s8v*>(arena + ad);
        }
#pragma unroll
        for (int n = 0; n < 4; ++n) {
          int row = n * 16 + (lane & 15);
          int ad = ((row << 7) + kk * 64 + ((lane >> 4) << 4)) ^ ((row & 7) << 4);
          bf[n] = *reinterpret_cast<const s8v*>(LBp + ad);
        }
#pragma unroll
        for (int m = 0; m < 4; ++m)
#pragma unroll
          for (int n = 0; n < 4; ++n)
            acc[m][n] = mfma16(af[m], bf[n], acc[m][n]);
      }
      __syncthreads();       // all reads done before restage / epilogue reuse
    }
  }
  // ---- S2b: v -> vTl, a-preact -> laBuf ----
  if (wave == 2) {
#pragma unroll
    for (int m = 0; m < 4; ++m)
#pragma unroll
      for (int n = 0; n < 4; ++n)
#pragma unroll
        for (int r = 0; r < 4; ++r) {
          int row = m * 16 + ((lane >> 4) << 2) + r;
          int col = n * 16 + (lane & 15);
          float vv = acc[m][n][r] + b_qkv[1024 + h * 64 + col];
          int adt = ((col << 7) + (row << 1)) ^ ((col & 7) << 4);
          *reinterpret_cast<short*>(vTl + adt) = (short)f2b(vv);
        }
  } else if (wave == 3) {
#pragma unroll
    for (int m = 0; m < 4; ++m)
#pragma unroll
      for (int n = 0; n < 4; ++n)
#pragma unroll
        for (int r = 0; r < 4; ++r) {
          int row = m * 16 + ((lane >> 4) << 2) + r;
          int col = n * 16 + (lane & 15);
          laBuf[row * 65 + col] = acc[m][n][r] + b_a[h * 64 + col];
        }
  }
  __syncthreads();
  // ---- S2c: chunk-local log-cumsum (all waves, 16 rows each; col = lane) ---
  {
    float la_loc[16]; float run = 0.f;
#pragma unroll
    for (int rr = 0; rr < 16; ++rr) {
      float xv = laBuf[(wave * 16 + rr) * 65 + lane];
      float a = 1.f / (1.f + expf(-xv));
      a = fminf(fmaxf(a, 1e-10f), 1.f);
      run += logf(a);
      la_loc[rr] = run;
    }
    wsumA[wave][lane] = run;
    __syncthreads();
    float prew = 0.f;
#pragma unroll
    for (int w = 0; w < 3; ++w) if (w < wave) prew += wsumA[w][lane];
#pragma unroll
    for (int rr = 0; rr < 16; ++rr)
      laBuf[(wave * 16 + rr) * 65 + lane] = prew + la_loc[rr];
    if (tid < 64) {
      float s = ((wsumA[0][tid] + wsumA[1][tid]) + wsumA[2][tid]) + wsumA[3][tid];
      csum[(((size_t)bh) * 32 + chunk) * 64 + tid] = s;
    }
  }
  post_flag(&fcsum[bh]);                   // csum[bh][chunk] published
  wait_flag(&fcsum[bh], 32);               // need all same-bh csum

  // ---- S3: gates (fp32) -> qL/kR/kT; kstate; scores; P; PV ----------------
  f32x4 accO[4] = {};
  {
    if (tid < 64) preArr[tid] = csum_prefix(csum, bh, chunk, tid);
    __syncthreads();
    if (wave == 0) {         // q-plane: q2 = (acc+b)*SCALE*exp(pre+la)
#pragma unroll
      for (int m = 0; m < 4; ++m)
#pragma unroll
        for (int n = 0; n < 4; ++n)
#pragma unroll
          for (int r = 0; r < 4; ++r) {
            int row = m * 16 + ((lane >> 4) << 2) + r;
            int col = n * 16 + (lane & 15);
            float g = expf(preArr[col] + laBuf[row * 65 + col]);
            float qv = (acc[m][n][r] + b_qkv[h * 64 + col]) * 0.125f * g;
            int adr = ((row << 7) + (col << 1)) ^ ((row & 7) << 4);
            *reinterpret_cast<short*>(qL + adr) = (short)f2b(qv);
          }
    } else if (wave == 1) {  // k-plane: k2 = (acc+b)/max(exp(pre+la),1e-8)
#pragma unroll
      for (int m = 0; m < 4; ++m)
#pragma unroll
        for (int n = 0; n < 4; ++n)
#pragma unroll
          for (int r = 0; r < 4; ++r) {
            int row = m * 16 + ((lane >> 4) << 2) + r;
            int col = n * 16 + (lane & 15);
            float gi = 1.f / fmaxf(expf(preArr[col] + laBuf[row * 65 + col]), 1e-8f);
            float kv = (acc[m][n][r] + b_qkv[512 + h * 64 + col]) * gi;
            unsigned short kb = f2b(kv);
            int adr = ((row << 7) + (col << 1)) ^ ((row & 7) << 4);
            int adt = ((col << 7) + (row << 1)) ^ ((col & 7) << 4);
            *reinterpret_cast<short*>(kR + adr) = (short)kb;
            *reinterpret_cast<short*>(kT + adt) = (short)kb;
          }
    }
    __syncthreads();
    // kstate: S^T[dd][d'] = sum_j v[j][dd] k2[j][d']
    f32x4 sacc[4] = {};
#pragma unroll
    for (int kk = 0; kk < 2; ++kk) {
      int arow = wave * 16 + (lane & 15);
      int aad = ((arow << 7) + kk * 64 + ((lane >> 4) << 4)) ^ ((arow & 7) << 4);
      s8v av = *reinterpret_cast<const s8v*>(vTl + aad);
#pragma unroll
      for (int n = 0; n < 4; ++n) {
        int brow = n * 16 + (lane & 15);
        int bad = ((brow << 7) + kk * 64 + ((lane >> 4) << 4)) ^ ((brow & 7) << 4);
        sacc[n] = mfma16(av, *reinterpret_cast<const s8v*>(kT + bad), sacc[n]);
      }
    }
    short* Sp = Sbuf + ((size_t)bh * 32 + chunk) * 4096;
#pragma unroll
    for (int n = 0; n < 4; ++n)
#pragma unroll
      for (int r = 0; r < 4; ++r)
        Sp[(wave * 16 + ((lane >> 4) << 2) + r) * 64 + n * 16 + (lane & 15)] = (short)f2b(sacc[n][r]);
    post_flag(&fS[bh]);                    // Sbuf[bh][chunk] published early
    // scores: sim[i][j] = q2[i]·k2[j]
    f32x4 accS[4] = {};
#pragma unroll
    for (int kk = 0; kk < 2; ++kk) {
      int arow = wave * 16 + (lane & 15);
      int aad = ((arow << 7) + kk * 64 + ((lane >> 4) << 4)) ^ ((arow & 7) << 4);
      s8v aq = *reinterpret_cast<const s8v*>(qL + aad);
#pragma unroll
      for (int n = 0; n < 4; ++n) {
        int brow = n * 16 + (lane & 15);
        int bad = ((brow << 7) + kk * 64 + ((lane >> 4) << 4)) ^ ((brow & 7) << 4);
        accS[n] = mfma16(aq, *reinterpret_cast<const s8v*>(kR + bad), accS[n]);
      }
    }
    __syncthreads();           // kT reads (kstate) done before P overwrites
#pragma unroll
    for (int n = 0; n < 4; ++n)
#pragma unroll
      for (int r = 0; r < 4; ++r) {
        int i = wave * 16 + ((lane >> 4) << 2) + r;
        int j = n * 16 + (lane & 15);
        float v = (j <= i) ? accS[n][r] : 0.f;
        int ad = ((i << 7) + (j << 1)) ^ ((i & 7) << 4);
        *reinterpret_cast<short*>(kT + ad) = (short)f2b(v);
      }
    __syncthreads();
    // PV: accO[i][d'] = sum_j P[i][j] v[j][d']
#pragma unroll
    for (int kk = 0; kk < 2; ++kk) {
      int arow = wave * 16 + (lane & 15);
      int aad = ((arow << 7) + kk * 64 + ((lane >> 4) << 4)) ^ ((arow & 7) << 4);
      s8v ap = *reinterpret_cast<const s8v*>(kT + aad);
#pragma unroll
      for (int n = 0; n < 4; ++n) {
        int brow = n * 16 + (lane & 15);
        int bad = ((brow << 7) + kk * 64 + ((lane >> 4) << 4)) ^ ((brow & 7) << 4);
        accO[n] = mfma16(ap, *reinterpret_cast<const s8v*>(vTl + bad), accO[n]);
      }
    }
  }
  wait_flag(&fS[bh], 32);                  // need all same-bh Sbuf

  // ---- S45: per-block Spre -> bf16 LDS; accO += q@Spre; aout --------------
  {
    char* LS = kR;             // kR dead since scores MFMA
    int srow = tid >> 2, scol0 = (tid & 3) * 16;
    const short* Sb = Sbuf + (size_t)bh * 32 * 4096 + srow * 64 + scol0;
    float acc0[8] = {}, acc1[8] = {};
#pragma unroll
    for (int c = 0; c < 32; ++c) {
      if (c < chunk) {
        s8v v0 = *reinterpret_cast<const s8v*>(Sb + (size_t)c * 4096);
        s8v v1 = *reinterpret_cast<const s8v*>(Sb + (size_t)c * 4096 + 8);
#pragma unroll
        for (int j = 0; j < 8; ++j) {
          acc0[j] += b2f((unsigned short)v0[j]);
          acc1[j] += b2f((unsigned short)v1[j]);
        }
      }
    }
    s8v o0, o1;
#pragma unroll
    for (int j = 0; j < 8; ++j) {
      o0[j] = (short)f2b(acc0[j]);
      o1[j] = (short)f2b(acc1[j]);
    }
    int byte0 = (srow << 7) + (scol0 << 1);
    int sw = (srow & 7) << 4;
    *reinterpret_cast<s8v*>(LS + ((byte0)      ^ sw)) = o0;
    *reinterpret_cast<s8v*>(LS + ((byte0 + 16) ^ sw)) = o1;
    __syncthreads();
#pragma unroll
    for (int kk = 0; kk < 2; ++kk) {
      int arow = wave * 16 + (lane & 15);
      int aad = ((arow << 7) + kk * 64 + ((lane >> 4) << 4)) ^ ((arow & 7) << 4);
      s8v aq = *reinterpret_cast<const s8v*>(qL + aad);
#pragma unroll
      for (int n = 0; n < 4; ++n) {
        int brow = n * 16 + (lane & 15);
        int bad = ((brow << 7) + kk * 64 + ((lane >> 4) << 4)) ^ ((brow & 7) << 4);
        accO[n] = mfma16(aq, *reinterpret_cast<const s8v*>(LS + bad), accO[n]);
      }
    }
#pragma unroll
    for (int n = 0; n < 4; ++n)
#pragma unroll
      for (int r = 0; r < 4; ++r) {
        int i = wave * 16 + ((lane >> 4) << 2) + r;
        int col = h * 64 + n * 16 + (lane & 15);
        size_t row = (size_t)b * 2048 + chunk * 64 + i;
        aout[row * 512 + col] = (short)f2b(accO[n][r]);
      }
  }
  post_flag(&fA[b * 32 + chunk]);          // aout rows (b,chunk) published

  // ---- S6: gemm1 (512 tiles of 64x64) ----
  {
    int xcd6 = bid & 7, rq = bid >> 3;
    int bx = rq & 7, by = xcd6 * 8 + (rq >> 3);
    wait_flag(&fA[by], 8);                 // all 8 heads of this row-chunk
    int m0 = by * 64, n0 = bx * 64;
    f32x4 a6[2][2] = {};
    gemm_core<64, 64, 2, 2>(aout, woT, arena, arena + 8192, m0, n0, tid, a6);
    int wr = (wave >> 1) * 32, wc = (wave & 1) * 32;
#pragma unroll
    for (int m = 0; m < 2; ++m)
#pragma unroll
      for (int n = 0; n < 2; ++n)
#pragma unroll
        for (int r = 0; r < 4; ++r) {
          int row = m0 + wr + m * 16 + ((lane >> 4) << 2) + r;
          int col = n0 + wc + n * 16 + (lane & 15);
          out[(size_t)row * 512 + col] = a6[m][n][r] + b_out[col];
        }
  }
}

// ---------------- fallback wrappers (R12 proven path) ------------------------
__global__ __launch_bounds__(256) void prep_k(const float* x, const float* gamma,
    short* xnb, const float* w_qkv, const float* w_a, const float* w_out,
    short* wT, short* woT) {
  __shared__ __align__(16) char arena[4224];
  st_prep(blockIdx.x, threadIdx.x, arena, x, gamma, xnb, w_qkv, w_a, w_out, wT, woT);
}
__global__ __launch_bounds__(256) void gemm0_k(const short* xnb, const short* wT,
    short* qkvb, const float* b_qkv, const float* b_a, float* araw, float* csum) {
  __shared__ __align__(16) char arena[24576];
  st_gemm0_fb(blockIdx.x, threadIdx.x, arena, xnb, wT, qkvb, b_qkv, b_a, araw, csum);
}
__global__ __launch_bounds__(256) void scan2_k(const short* qkvb, const float* araw,
    const float* csum, short* q2, short* k2, short* vT, short* Sbuf) {
  __shared__ __align__(16) char arena[32768];
  st_scan2(blockIdx.x, threadIdx.x, arena, qkvb, araw, csum, q2, k2, vT, Sbuf);
}
__global__ __launch_bounds__(256) void sprefix_k(const short* Sbuf, short* Spre) {
  st_sprefix(blockIdx.x, threadIdx.x, Sbuf, Spre);
}
__global__ __launch_bounds__(256) void attnk_k(const short* q2, const short* k2,
    const short* vT, const short* Spre, short* aout) {
  __shared__ __align__(16) char arena[32768];
  st_attnk(blockIdx.x, threadIdx.x, arena, q2, k2, vT, Spre, aout);
}
__global__ __launch_bounds__(256) void gemm1_k(const short* aout, const short* woT,
    float* out, const float* b_out) {
  __shared__ __align__(16) char arena[12288];
  st_gemm1_fb(blockIdx.x, threadIdx.x, arena, aout, woT, out, b_out);
}

// ---------------------------------------------------------------------------
extern "C" void kernel_launch(void* const* d_in, const int* in_sizes, int n_in,
                              void* d_out, int out_size, void* d_ws, size_t ws_size,
                              hipStream_t stream) {
  const float* x     = (const float*)d_in[0];
  const float* gamma = (const float*)d_in[1];
  const float* w_qkv = (const float*)d_in[2];
  const float* b_qkv = (const float*)d_in[3];
  const float* w_a   = (const float*)d_in[4];
  const float* b_a   = (const float*)d_in[5];
  const float* w_out = (const float*)d_in[6];
  const float* b_out = (const float*)d_in[7];
  float* out = (float*)d_out;
  char* ws = (char*)d_ws;

  const size_t MB = 1u << 20;
  short* xnb  = (short*)(ws);                 // 4 MiB   [4096][512] bf16
  short* wT   = (short*)(ws + 4  * MB);       // 2 MiB   [2048][512] bf16
  short* woT  = (short*)(ws + 6  * MB);       // 0.5 MiB [512][512]  bf16
  float* csum = (float*)(ws + 7  * MB);       // 128 KiB [16][32][64] f32
  short* Sbuf = (short*)(ws + 8  * MB);       // 4 MiB   [16][32][64][64] bf16
  short* aout = (short*)(ws + 12 * MB);       // 4 MiB   [4096][512] bf16
  // fallback-only buffers:
  short* qkvb = (short*)(ws + 16 * MB);       // 12 MiB
  float* araw = (float*)(ws + 28 * MB);       // 8 MiB
  short* Spre = (short*)(ws + 36 * MB);       // 4 MiB
  short* q2   = (short*)(ws + 40 * MB);       // 4 MiB
  short* k2   = (short*)(ws + 44 * MB);       // 4 MiB
  short* vT   = (short*)(ws + 48 * MB);       // 4 MiB
  int*   flags = (int*)(ws + 52 * MB);        // 96 ints (mega path only)

  int dev = 0; (void)hipGetDevice(&dev);
  int coop = 0;
  (void)hipDeviceGetAttribute(&coop, hipDeviceAttributeCooperativeLaunch, dev);
  int nb = 0;
  (void)hipOccupancyMaxActiveBlocksPerMultiprocessor(&nb, mega_k, 256, 0);

  hipError_t err = hipErrorUnknown;
  if (coop && nb >= 2) {
    void* args[] = {&x, &gamma, &w_qkv, &b_qkv, &w_a, &b_a, &w_out, &b_out,
                    &out, &xnb, &wT, &woT, &csum, &Sbuf, &aout, &flags};
    err = hipLaunchCooperativeKernel((void*)mega_k, dim3(512), dim3(256), args, 0, stream);
  }
  if (err != hipSuccess) {
    prep_k   <<<2304, 256, 0, stream>>>(x, gamma, xnb, w_qkv, w_a, w_out, wT, woT);
    gemm0_k  <<<1024, 256, 0, stream>>>(xnb, wT, qkvb, b_qkv, b_a, araw, csum);
    scan2_k  <<<512,  256, 0, stream>>>(qkvb, araw, csum, q2, k2, vT, Sbuf);
    sprefix_k<<<256,  256, 0, stream>>>(Sbuf, Spre);
    attnk_k  <<<512,  256, 0, stream>>>(q2, k2, vT, Spre, aout);
    gemm1_k  <<<1024, 256, 0, stream>>>(aout, woT, out, b_out);
  }
}

// Round 16
// 58.200 us; speedup vs baseline: 1.0198x; 1.0198x over previous
//
#include <hip/hip_runtime.h>
#include <hip/hip_cooperative_groups.h>

// ---------------------------------------------------------------------------
// CausalFullAttention (decay-gated causal linear attention), MI355X gfx950
// b=2, n=2048, DIM=512, HEADS=8, DIM_HEAD=64
// R16: == R15 + (1) s_setprio(1) around MFMA clusters (T5; wave role-split
//      schedule), (2) XCD remap: 8 same-(b,chunk) h-blocks share an XCD so
//      the A-panel (xnb rows) is L2-local; B (2MB) fits every L2, (3) S1
//      compaction: rmsnorm 8 rows/unit -> 1792 units (3.5 rounds).
//      Fallback = R12's proven 6-kernel path.
// ---------------------------------------------------------------------------

namespace cg = cooperative_groups;

using s8v   = __attribute__((ext_vector_type(8))) short;   // 8 x bf16 bits
using f32x4 = __attribute__((ext_vector_type(4))) float;

__device__ __forceinline__ unsigned short f2b(float f) {
  unsigned int u = __builtin_bit_cast(unsigned int, f);
  u += 0x7FFFu + ((u >> 16) & 1u);          // RNE
  return (unsigned short)(u >> 16);
}
__device__ __forceinline__ float b2f(unsigned short b) {
  unsigned int u = ((unsigned int)b) << 16;
  return __builtin_bit_cast(float, u);
}
__device__ __forceinline__ f32x4 mfma16(s8v a, s8v b, f32x4 c) {
  return __builtin_amdgcn_mfma_f32_16x16x32_bf16(a, b, c, 0, 0, 0);
}
__device__ __forceinline__ void gload16(const void* g, void* l) {
  __builtin_amdgcn_global_load_lds(
      (const __attribute__((address_space(1))) void*)g,
      (__attribute__((address_space(3))) void*)l, 16, 0, 0);
}

// ---- producer/consumer flag sync (device scope) ----------------------------
__device__ __forceinline__ void post_flag(int* f) {
  __threadfence();                         // all threads: publish data writes
  __syncthreads();                         // everyone's writes+fence done
  if (threadIdx.x == 0)
    __hip_atomic_fetch_add(f, 1, __ATOMIC_RELEASE, __HIP_MEMORY_SCOPE_AGENT);
}
__device__ __forceinline__ void wait_flag(int* f, int target) {
  if (threadIdx.x == 0) {
    while (__hip_atomic_load(f, __ATOMIC_ACQUIRE, __HIP_MEMORY_SCOPE_AGENT) < target)
      __builtin_amdgcn_s_sleep(2);
  }
  __syncthreads();
}

// ---------------- stage: prep (rmsnorm u<512 (8 rows) | wtrans u>=512) -------
__device__ __forceinline__ void st_prep(int u, int tid, char* arena,
    const float* __restrict__ x, const float* __restrict__ gamma,
    short* __restrict__ xnb,
    const float* __restrict__ w_qkv, const float* __restrict__ w_a,
    const float* __restrict__ w_out,
    short* __restrict__ wT, short* __restrict__ woT) {
  int lane = tid & 63, wave = tid >> 6;
  if (u < 512) {
#pragma unroll
    for (int rr = 0; rr < 2; ++rr) {
      int row = u * 8 + wave * 2 + rr;
      const float4* xp = reinterpret_cast<const float4*>(x + (size_t)row * 512 + lane * 8);
      float4 v0 = xp[0], v1 = xp[1];
      float ss = v0.x*v0.x + v0.y*v0.y + v0.z*v0.z + v0.w*v0.w
               + v1.x*v1.x + v1.y*v1.y + v1.z*v1.z + v1.w*v1.w;
#pragma unroll
      for (int off = 32; off > 0; off >>= 1) ss += __shfl_xor(ss, off, 64);
      float s = 22.627416997969522f / fmaxf(sqrtf(ss), 1e-12f);
      const float* g = gamma + lane * 8;
      float vals[8] = {v0.x, v0.y, v0.z, v0.w, v1.x, v1.y, v1.z, v1.w};
      s8v o;
#pragma unroll
      for (int j = 0; j < 8; ++j) o[j] = (short)f2b(vals[j] * s * g[j]);
      *reinterpret_cast<s8v*>(xnb + (size_t)row * 512 + lane * 8) = o;
    }
  } else {
    float (*t)[33] = reinterpret_cast<float (*)[33]>(arena);
    int id = u - 512;                      // 0..1279
    int bx = id % 80, k0 = (id / 80) * 32;
    const float* src; short* dst; int N, n0;
    if (bx < 48)      { src = w_qkv; dst = wT;                      N = 1536; n0 = bx * 32; }
    else if (bx < 64) { src = w_a;   dst = wT + (size_t)1536 * 512; N = 512;  n0 = (bx - 48) * 32; }
    else              { src = w_out; dst = woT;                     N = 512;  n0 = (bx - 64) * 32; }
    int tx = tid & 31, ty = tid >> 5;
    __syncthreads();   // prior arena use complete
#pragma unroll
    for (int i = 0; i < 4; ++i)
      t[ty + 8 * i][tx] = src[(size_t)(k0 + ty + 8 * i) * N + n0 + tx];
    __syncthreads();
#pragma unroll
    for (int i = 0; i < 4; ++i)
      dst[(size_t)(n0 + ty + 8 * i) * 512 + k0 + tx] = (short)f2b(t[tx][ty + 8 * i]);
  }
}

// ---------------- single-buffered GEMM core (m97 structure), WRxWC waves -----
template <int BM, int BN, int WR, int WC>
__device__ __forceinline__ void gemm_core(const short* __restrict__ A,
                                          const short* __restrict__ Bm,
                                          char* LA, char* LB,
                                          int m0, int n0, int tid,
                                          f32x4 (&acc)[BM / WR / 16][BN / WC / 16]) {
  constexpr int WM = BM / WR, WN = BN / WC, FM = WM / 16, FN = WN / 16;
  const int lane = tid & 63, wave = tid >> 6;
  const int wr = (wave / WC) * WM, wc = (wave % WC) * WN;
#pragma unroll 1
  for (int t = 0; t < 8; ++t) {            // K = 512, BK = 64
    const int k0 = t * 64;
#pragma unroll
    for (int r = 0; r < BM / 32; ++r) {
      int o = r * 4096 + tid * 16;
      int row = o >> 7;
      int ce = (((o & 127) ^ ((row & 7) << 4)) >> 1);   // pre-swizzled src col
      gload16(A + (size_t)(m0 + row) * 512 + k0 + ce, LA + o);
    }
#pragma unroll
    for (int r = 0; r < BN / 32; ++r) {
      int o = r * 4096 + tid * 16;
      int row = o >> 7;
      int ce = (((o & 127) ^ ((row & 7) << 4)) >> 1);
      gload16(Bm + (size_t)(n0 + row) * 512 + k0 + ce, LB + o);
    }
    __syncthreads();                       // tile ready (vmcnt drained)
    __builtin_amdgcn_s_setprio(1);
#pragma unroll
    for (int kk = 0; kk < 2; ++kk) {
      s8v af[FM], bf[FN];
#pragma unroll
      for (int m = 0; m < FM; ++m) {
        int row = wr + m * 16 + (lane & 15);
        int ad = ((row << 7) + kk * 64 + ((lane >> 4) << 4)) ^ ((row & 7) << 4);
        af[m] = *reinterpret_cast<const s8v*>(LA + ad);
      }
#pragma unroll
      for (int n = 0; n < FN; ++n) {
        int row = wc + n * 16 + (lane & 15);
        int ad = ((row << 7) + kk * 64 + ((lane >> 4) << 4)) ^ ((row & 7) << 4);
        bf[n] = *reinterpret_cast<const s8v*>(LB + ad);
      }
#pragma unroll
      for (int m = 0; m < FM; ++m)
#pragma unroll
        for (int n = 0; n < FN; ++n)
          acc[m][n] = mfma16(af[m], bf[n], acc[m][n]);
    }
    __builtin_amdgcn_s_setprio(0);
    if (t + 1 < 8) __syncthreads();        // reads done before next overwrite
  }
}

// chunk-prefix over csum with fixed-32 unroll (independent loads, masked add)
__device__ __forceinline__ float csum_prefix(const float* __restrict__ csum,
                                             int bh, int chunk, int d) {
  float pre = 0.f;
#pragma unroll
  for (int c = 0; c < 32; ++c) {
    float cv = csum[((size_t)bh * 32 + c) * 64 + d];
    pre += (c < chunk) ? cv : 0.f;
  }
  return pre;
}

// ================== FALLBACK stages (R12 path, proven) =======================
__device__ __forceinline__ void st_gemm0_fb(int vid, int tid, char* arena,
    const short* __restrict__ xnb, const short* __restrict__ wT,
    short* __restrict__ qkvb, const float* __restrict__ b_qkv,
    const float* __restrict__ b_a, float* __restrict__ araw,
    float* __restrict__ csum) {
  const int lane = tid & 63, wave = tid >> 6;
  int xcd = vid & 7, rq = vid >> 3;
  int bx = rq & 31, by = xcd * 4 + (rq >> 5);
  int m0 = by * 128, n0 = bx * 64;
  f32x4 acc[2][4] = {};
  gemm_core<128, 64, 4, 1>(xnb, wT, arena, arena + 16384, m0, n0, tid, acc);
  int wr = wave * 32;
  if (n0 < 1536) {
#pragma unroll
    for (int m = 0; m < 2; ++m)
#pragma unroll
      for (int n = 0; n < 4; ++n)
#pragma unroll
        for (int r = 0; r < 4; ++r) {
          int row = m0 + wr + m * 16 + ((lane >> 4) << 2) + r;
          int col = n0 + n * 16 + (lane & 15);
          float v = acc[m][n][r] + b_qkv[col];
          int w = col >> 9, h = (col >> 6) & 7, d = col & 63;
          int b = row >> 11, nn = row & 2047;
          qkvb[((((size_t)(w * 2 + b)) * 8 + h) * 2048 + nn) * 64 + d] = (short)f2b(v);
        }
  } else {
    __syncthreads();
    float (*WSUM)[64] = reinterpret_cast<float (*)[64]>(arena);
    float cs[4] = {};
    int b = m0 >> 11;
#pragma unroll
    for (int m = 0; m < 2; ++m)
#pragma unroll
      for (int n = 0; n < 4; ++n)
#pragma unroll
        for (int r = 0; r < 4; ++r) {
          int row = m0 + wr + m * 16 + ((lane >> 4) << 2) + r;
          int gc = n0 + n * 16 + (lane & 15) - 1536;
          int h = gc >> 6, d = gc & 63, nn = row & 2047;
          float xv = acc[m][n][r] + b_a[gc];
          araw[((size_t)(b * 8 + h) * 2048 + nn) * 64 + d] = xv;
          float a = 1.f / (1.f + expf(-xv));
          a = fminf(fmaxf(a, 1e-10f), 1.f);
          cs[n] += logf(a);
        }
#pragma unroll
    for (int n = 0; n < 4; ++n) {
      cs[n] += __shfl_xor(cs[n], 16, 64);
      cs[n] += __shfl_xor(cs[n], 32, 64);
    }
    if (lane < 16) {
#pragma unroll
      for (int n = 0; n < 4; ++n) WSUM[wave][n * 16 + lane] = cs[n];
    }
    __syncthreads();
    if (tid < 128) {
      int cl = tid >> 6, col = tid & 63;
      float s = WSUM[2 * cl][col] + WSUM[2 * cl + 1][col];
      int h = (n0 - 1536) >> 6;
      int chunkg = ((m0 & 2047) >> 6) + cl;
      csum[(((size_t)(b * 8 + h)) * 32 + chunkg) * 64 + col] = s;
    }
  }
}

__device__ __forceinline__ void st_scan2(int vid, int tid, char* arena,
    const short* __restrict__ qkvb, const float* __restrict__ araw,
    const float* __restrict__ csum, short* __restrict__ q2,
    short* __restrict__ k2, short* __restrict__ vT, short* __restrict__ Sbuf) {
  int chunk = vid & 31, bh = vid >> 5;
  int lane = tid & 63, wave = tid >> 6, d = lane;
  short (*kL)[64] = reinterpret_cast<short (*)[64]>(arena);
  short (*vL)[64] = reinterpret_cast<short (*)[64]>(arena + 8192);
  char* kT  = arena + 16384;
  char* vTl = arena + 24576;
  float (*wsum)[64] = reinterpret_cast<float (*)[64]>(arena + 16384);
  float pre = csum_prefix(csum, bh, chunk, d);
  const float* ap = araw + ((size_t)bh * 2048 + chunk * 64 + wave * 16) * 64 + d;
  float la[16]; float run = 0.f;
#pragma unroll
  for (int rr = 0; rr < 16; ++rr) {
    float xv = ap[rr * 64];
    float a = 1.f / (1.f + expf(-xv));
    a = fminf(fmaxf(a, 1e-10f), 1.f);
    run += logf(a);
    la[rr] = run;
  }
  wsum[wave][d] = run;
  __syncthreads();
#pragma unroll
  for (int w = 0; w < 3; ++w) if (w < wave) pre += wsum[w][d];
  const size_t WS = (size_t)2 * 8 * 2048 * 64;
  size_t base = ((size_t)bh * 2048 + chunk * 64 + wave * 16) * 64 + d;
#pragma unroll 4
  for (int rr = 0; rr < 16; ++rr) {
    int r = wave * 16 + rr;
    float g = expf(pre + la[rr]);
    float gi = 1.f / fmaxf(g, 1e-8f);
    float qv = b2f((unsigned short)qkvb[base + rr * 64]);
    float kv = b2f((unsigned short)qkvb[base + WS + rr * 64]);
    short vb = qkvb[base + 2 * WS + rr * 64];
    q2[base + rr * 64] = (short)f2b(qv * 0.125f * g);
    unsigned short kb = f2b(kv * gi);
    k2[base + rr * 64] = (short)kb;
    kL[r][d] = (short)kb;
    vL[r][d] = vb;
  }
  __syncthreads();
  short* vTrow = vT + ((size_t)bh * 64 + d) * 2048 + chunk * 64;
#pragma unroll
  for (int gg = 0; gg < 2; ++gg) {
    int g8 = wave + gg * 4;
    s8v pk, pv;
#pragma unroll
    for (int j = 0; j < 8; ++j) { pk[j] = kL[g8 * 8 + j][d]; pv[j] = vL[g8 * 8 + j][d]; }
    *reinterpret_cast<s8v*>(vTrow + g8 * 8) = pv;
    int ad = ((d << 7) + g8 * 16) ^ ((d & 7) << 4);
    *reinterpret_cast<s8v*>(kT  + ad) = pk;
    *reinterpret_cast<s8v*>(vTl + ad) = pv;
  }
  __syncthreads();
  f32x4 acc[4] = {};
#pragma unroll
  for (int kk = 0; kk < 2; ++kk) {
    int arow = wave * 16 + (lane & 15);
    int aad = ((arow << 7) + kk * 64 + ((lane >> 4) << 4)) ^ ((arow & 7) << 4);
    s8v av = *reinterpret_cast<const s8v*>(vTl + aad);
#pragma unroll
    for (int n = 0; n < 4; ++n) {
      int brow = n * 16 + (lane & 15);
      int bad = ((brow << 7) + kk * 64 + ((lane >> 4) << 4)) ^ ((brow & 7) << 4);
      acc[n] = mfma16(av, *reinterpret_cast<const s8v*>(kT + bad), acc[n]);
    }
  }
  short* Sp = Sbuf + ((size_t)bh * 32 + chunk) * 4096;
#pragma unroll
  for (int n = 0; n < 4; ++n)
#pragma unroll
    for (int r = 0; r < 4; ++r)
      Sp[(wave * 16 + ((lane >> 4) << 2) + r) * 64 + n * 16 + (lane & 15)] = (short)f2b(acc[n][r]);
}

__device__ __forceinline__ void st_sprefix(int vid, int tid,
    const short* __restrict__ Sbuf, short* __restrict__ Spre) {
  int bh = vid >> 4;
  int e = ((vid & 15) << 8) + tid;
  size_t base = (size_t)bh * 32 * 4096 + e;
  unsigned short v[32];
#pragma unroll
  for (int c = 0; c < 32; ++c)
    v[c] = (unsigned short)Sbuf[base + (size_t)c * 4096];
  float acc = 0.f;
#pragma unroll
  for (int c = 0; c < 32; ++c) {
    Spre[base + (size_t)c * 4096] = (short)f2b(acc);
    acc += b2f(v[c]);
  }
}

__device__ __forceinline__ void st_attnk(int vid, int tid, char* arena,
    const short* __restrict__ q2, const short* __restrict__ k2,
    const short* __restrict__ vT, const short* __restrict__ Spre,
    short* __restrict__ aout) {
  int chunk = vid & 31, bh = vid >> 5;
  int lane = tid & 63, wave = tid >> 6;
  char* LQ = arena;              // later reused for P
  char* LK = arena + 8192;
  char* LV = arena + 16384;
  char* LS = arena + 24576;
#pragma unroll
  for (int rr = 0; rr < 2; ++rr) {
    int o = rr * 4096 + tid * 16;
    int row = o >> 7;
    int ce = (((o & 127) ^ ((row & 7) << 4)) >> 1);
    gload16(q2   + ((size_t)bh * 2048 + chunk * 64 + row) * 64 + ce, LQ + o);
    gload16(k2   + ((size_t)bh * 2048 + chunk * 64 + row) * 64 + ce, LK + o);
    gload16(vT   + ((size_t)bh * 64 + row) * 2048 + chunk * 64 + ce, LV + o);
    gload16(Spre + (((size_t)bh * 32 + chunk) * 64 + row) * 64 + ce, LS + o);
  }
  __syncthreads();
  f32x4 accS[4] = {}, accO[4] = {};
#pragma unroll
  for (int kk = 0; kk < 2; ++kk) {
    int arow = wave * 16 + (lane & 15);
    int aad = ((arow << 7) + kk * 64 + ((lane >> 4) << 4)) ^ ((arow & 7) << 4);
    s8v aq = *reinterpret_cast<const s8v*>(LQ + aad);
#pragma unroll
    for (int n = 0; n < 4; ++n) {
      int brow = n * 16 + (lane & 15);
      int bad = ((brow << 7) + kk * 64 + ((lane >> 4) << 4)) ^ ((brow & 7) << 4);
      accS[n] = mfma16(aq, *reinterpret_cast<const s8v*>(LK + bad), accS[n]);
      accO[n] = mfma16(aq, *reinterpret_cast<const s8v*>(LS + bad), accO[n]);
    }
  }
  __syncthreads();
#pragma unroll
  for (int n = 0; n < 4; ++n)
#pragma unroll
    for (int r = 0; r < 4; ++r) {
      int i = wave * 16 + ((lane >> 4) << 2) + r;
      int j = n * 16 + (lane & 15);
      float v = (j <= i) ? accS[n][r] : 0.f;
      int ad = ((i << 7) + (j << 1)) ^ ((i & 7) << 4);
      *reinterpret_cast<short*>(LQ + ad) = (short)f2b(v);
    }
  __syncthreads();
#pragma unroll
  for (int kk = 0; kk < 2; ++kk) {
    int arow = wave * 16 + (lane & 15);
    int aad = ((arow << 7) + kk * 64 + ((lane >> 4) << 4)) ^ ((arow & 7) << 4);
    s8v ap = *reinterpret_cast<const s8v*>(LQ + aad);
#pragma unroll
    for (int n = 0; n < 4; ++n) {
      int brow = n * 16 + (lane & 15);
      int bad = ((brow << 7) + kk * 64 + ((lane >> 4) << 4)) ^ ((brow & 7) << 4);
      accO[n] = mfma16(ap, *reinterpret_cast<const s8v*>(LV + bad), accO[n]);
    }
  }
  int b = bh >> 3, h = bh & 7;
#pragma unroll
  for (int n = 0; n < 4; ++n)
#pragma unroll
    for (int r = 0; r < 4; ++r) {
      int i = wave * 16 + ((lane >> 4) << 2) + r;
      int col = h * 64 + n * 16 + (lane & 15);
      size_t row = (size_t)b * 2048 + chunk * 64 + i;
      aout[row * 512 + col] = (short)f2b(accO[n][r]);
    }
}

__device__ __forceinline__ void st_gemm1_fb(int vid, int tid, char* arena,
    const short* __restrict__ aout, const short* __restrict__ woT,
    float* __restrict__ out, const float* __restrict__ b_out) {
  const int lane = tid & 63, wave = tid >> 6;
  int xcd = vid & 7, rq = vid >> 3;
  int bx = rq & 15, by = xcd * 8 + (rq >> 4);
  int m0 = by * 64, n0 = bx * 32;
  f32x4 acc[1][2] = {};
  gemm_core<64, 32, 4, 1>(aout, woT, arena, arena + 8192, m0, n0, tid, acc);
  int wr = wave * 16;
#pragma unroll
  for (int n = 0; n < 2; ++n)
#pragma unroll
    for (int r = 0; r < 4; ++r) {
      int row = m0 + wr + ((lane >> 4) << 2) + r;
      int col = n0 + n * 16 + (lane & 15);
      out[(size_t)row * 512 + col] = acc[0][n][r] + b_out[col];
    }
}

// ================== mega kernel (cooperative, fused, flag-synced) ============
__global__ __launch_bounds__(256, 2) void mega_k(
    const float* __restrict__ x, const float* __restrict__ gamma,
    const float* __restrict__ w_qkv, const float* __restrict__ b_qkv,
    const float* __restrict__ w_a, const float* __restrict__ b_a,
    const float* __restrict__ w_out, const float* __restrict__ b_out,
    float* __restrict__ out,
    short* __restrict__ xnb, short* __restrict__ wT, short* __restrict__ woT,
    float* __restrict__ csum, short* __restrict__ Sbuf, short* __restrict__ aout,
    int* __restrict__ flags) {
  __shared__ __align__(16) char arena[57600];
  cg::grid_group grid = cg::this_grid();
  const int bid = blockIdx.x, tid = threadIdx.x;
  const int lane = tid & 63, wave = tid >> 6;
  int* fcsum = flags;          // [16]  posts: 32 each
  int* fS    = flags + 16;     // [16]  posts: 32 each
  int* fA    = flags + 32;     // [64]  posts: 8 each

  // ---- S1: prep (1792 units over 512 blocks) + flag zeroing ----
  if (bid == 0 && tid < 96) flags[tid] = 0;
  for (int u = bid; u < 1792; u += 512)
    st_prep(u, tid, arena, x, gamma, xnb, w_qkv, w_a, w_out, wT, woT);
  __threadfence(); grid.sync();            // weights + zeroed flags visible

  // ---- unit mapping: 8 same-(b,chunk) h-blocks share one XCD --------------
  const int xcd = bid & 7, i = bid >> 3;
  const int g = xcd * 8 + (i >> 3);        // (b,chunk) group 0..63
  const int h = i & 7;
  const int b = g >> 5, chunk = g & 31;
  const int bh = b * 8 + h;

  char* qL  = arena;
  char* kR  = arena + 8192;
  char* kT  = arena + 16384;
  char* vTl = arena + 24576;
  float* laBuf = reinterpret_cast<float*>(arena + 40960);   // [64][65]
  float (*wsumA)[64] = reinterpret_cast<float (*)[64]>(arena + 32768);
  float* preArr = reinterpret_cast<float*>(arena + 32768);

  // ---- S2a: fused 4-plane GEMM (wave w = plane w: 0=q,1=k,2=v,3=a) --------
  f32x4 acc[4][4] = {};
  {
    const int m0g = b * 2048 + chunk * 64;
    char* LBp = arena + 8192 + wave * 8192;
#pragma unroll 1
    for (int t = 0; t < 8; ++t) {
      int k0 = t * 64;
#pragma unroll
      for (int r = 0; r < 2; ++r) {
        int o = r * 4096 + tid * 16;
        int row = o >> 7;
        int ce = (((o & 127) ^ ((row & 7) << 4)) >> 1);
        gload16(xnb + (size_t)(m0g + row) * 512 + k0 + ce, arena + o);
      }
#pragma unroll
      for (int p = 0; p < 4; ++p)
#pragma unroll
        for (int r = 0; r < 2; ++r) {
          int o = r * 4096 + tid * 16;
          int row = o >> 7;
          int ce = (((o & 127) ^ ((row & 7) << 4)) >> 1);
          gload16(wT + (size_t)(p * 512 + h * 64 + row) * 512 + k0 + ce,
                  arena + 8192 + p * 8192 + o);
        }
      __syncthreads();
      __builtin_amdgcn_s_setprio(1);
#pragma unroll
      for (int kk = 0; kk < 2; ++kk) {
        s8v af[4], bf[4];
#pragma unroll
        for (int m = 0; m < 4; ++m) {
          int row = m * 16 + (lane & 15);
          int ad = ((row << 7) + kk * 64 + ((lane >> 4) << 4)) ^ ((row & 7) << 4);
          af[m] = *reinterpret_cast<const s8v*>(arena + ad);
        }
#pragma unroll
        for (int n = 0; n < 4; ++n) {
          int row = n * 16 + (lane & 15);
          int ad = ((row << 7) + kk * 64 + ((lane >> 4) << 4)) ^ ((row & 7) << 4);
          bf[n] = *reinterpret_cast<const s8v*>(LBp + ad);
        }
#pragma unroll
        for (int m = 0; m < 4; ++m)
#pragma unroll
          for (int n = 0; n < 4; ++n)
            acc[m][n] = mfma16(af[m], bf[n], acc[m][n]);
      }
      __builtin_amdgcn_s_setprio(0);
      __syncthreads();       // all reads done before restage / epilogue reuse
    }
  }
  // ---- S2b: v -> vTl, a-preact -> laBuf ----
  if (wave == 2) {
#pragma unroll
    for (int m = 0; m < 4; ++m)
#pragma unroll
      for (int n = 0; n < 4; ++n)
#pragma unroll
        for (int r = 0; r < 4; ++r) {
          int row = m * 16 + ((lane >> 4) << 2) + r;
          int col = n * 16 + (lane & 15);
          float vv = acc[m][n][r] + b_qkv[1024 + h * 64 + col];
          int adt = ((col << 7) + (row << 1)) ^ ((col & 7) << 4);
          *reinterpret_cast<short*>(vTl + adt) = (short)f2b(vv);
        }
  } else if (wave == 3) {
#pragma unroll
    for (int m = 0; m < 4; ++m)
#pragma unroll
      for (int n = 0; n < 4; ++n)
#pragma unroll
        for (int r = 0; r < 4; ++r) {
          int row = m * 16 + ((lane >> 4) << 2) + r;
          int col = n * 16 + (lane & 15);
          laBuf[row * 65 + col] = acc[m][n][r] + b_a[h * 64 + col];
        }
  }
  __syncthreads();
  // ---- S2c: chunk-local log-cumsum (all waves, 16 rows each; col = lane) ---
  {
    float la_loc[16]; float run = 0.f;
#pragma unroll
    for (int rr = 0; rr < 16; ++rr) {
      float xv = laBuf[(wave * 16 + rr) * 65 + lane];
      float a = 1.f / (1.f + expf(-xv));
      a = fminf(fmaxf(a, 1e-10f), 1.f);
      run += logf(a);
      la_loc[rr] = run;
    }
    wsumA[wave][lane] = run;
    __syncthreads();
    float prew = 0.f;
#pragma unroll
    for (int w = 0; w < 3; ++w) if (w < wave) prew += wsumA[w][lane];
#pragma unroll
    for (int rr = 0; rr < 16; ++rr)
      laBuf[(wave * 16 + rr) * 65 + lane] = prew + la_loc[rr];
    if (tid < 64) {
      float s = ((wsumA[0][tid] + wsumA[1][tid]) + wsumA[2][tid]) + wsumA[3][tid];
      csum[(((size_t)bh) * 32 + chunk) * 64 + tid] = s;
    }
  }
  post_flag(&fcsum[bh]);                   // csum[bh][chunk] published
  wait_flag(&fcsum[bh], 32);               // need all same-bh csum

  // ---- S3: gates (fp32) -> qL/kR/kT; kstate; scores; P; PV ----------------
  f32x4 accO[4] = {};
  {
    if (tid < 64) preArr[tid] = csum_prefix(csum, bh, chunk, tid);
    __syncthreads();
    if (wave == 0) {         // q-plane: q2 = (acc+b)*SCALE*exp(pre+la)
#pragma unroll
      for (int m = 0; m < 4; ++m)
#pragma unroll
        for (int n = 0; n < 4; ++n)
#pragma unroll
          for (int r = 0; r < 4; ++r) {
            int row = m * 16 + ((lane >> 4) << 2) + r;
            int col = n * 16 + (lane & 15);
            float g2 = expf(preArr[col] + laBuf[row * 65 + col]);
            float qv = (acc[m][n][r] + b_qkv[h * 64 + col]) * 0.125f * g2;
            int adr = ((row << 7) + (col << 1)) ^ ((row & 7) << 4);
            *reinterpret_cast<short*>(qL + adr) = (short)f2b(qv);
          }
    } else if (wave == 1) {  // k-plane: k2 = (acc+b)/max(exp(pre+la),1e-8)
#pragma unroll
      for (int m = 0; m < 4; ++m)
#pragma unroll
        for (int n = 0; n < 4; ++n)
#pragma unroll
          for (int r = 0; r < 4; ++r) {
            int row = m * 16 + ((lane >> 4) << 2) + r;
            int col = n * 16 + (lane & 15);
            float gi = 1.f / fmaxf(expf(preArr[col] + laBuf[row * 65 + col]), 1e-8f);
            float kv = (acc[m][n][r] + b_qkv[512 + h * 64 + col]) * gi;
            unsigned short kb = f2b(kv);
            int adr = ((row << 7) + (col << 1)) ^ ((row & 7) << 4);
            int adt = ((col << 7) + (row << 1)) ^ ((col & 7) << 4);
            *reinterpret_cast<short*>(kR + adr) = (short)kb;
            *reinterpret_cast<short*>(kT + adt) = (short)kb;
          }
    }
    __syncthreads();
    // kstate: S^T[dd][d'] = sum_j v[j][dd] k2[j][d']
    f32x4 sacc[4] = {};
    __builtin_amdgcn_s_setprio(1);
#pragma unroll
    for (int kk = 0; kk < 2; ++kk) {
      int arow = wave * 16 + (lane & 15);
      int aad = ((arow << 7) + kk * 64 + ((lane >> 4) << 4)) ^ ((arow & 7) << 4);
      s8v av = *reinterpret_cast<const s8v*>(vTl + aad);
#pragma unroll
      for (int n = 0; n < 4; ++n) {
        int brow = n * 16 + (lane & 15);
        int bad = ((brow << 7) + kk * 64 + ((lane >> 4) << 4)) ^ ((brow & 7) << 4);
        sacc[n] = mfma16(av, *reinterpret_cast<const s8v*>(kT + bad), sacc[n]);
      }
    }
    __builtin_amdgcn_s_setprio(0);
    short* Sp = Sbuf + ((size_t)bh * 32 + chunk) * 4096;
#pragma unroll
    for (int n = 0; n < 4; ++n)
#pragma unroll
      for (int r = 0; r < 4; ++r)
        Sp[(wave * 16 + ((lane >> 4) << 2) + r) * 64 + n * 16 + (lane & 15)] = (short)f2b(sacc[n][r]);
    post_flag(&fS[bh]);                    // Sbuf[bh][chunk] published early
    // scores: sim[i][j] = q2[i]·k2[j]
    f32x4 accS[4] = {};
    __builtin_amdgcn_s_setprio(1);
#pragma unroll
    for (int kk = 0; kk < 2; ++kk) {
      int arow = wave * 16 + (lane & 15);
      int aad = ((arow << 7) + kk * 64 + ((lane >> 4) << 4)) ^ ((arow & 7) << 4);
      s8v aq = *reinterpret_cast<const s8v*>(qL + aad);
#pragma unroll
      for (int n = 0; n < 4; ++n) {
        int brow = n * 16 + (lane & 15);
        int bad = ((brow << 7) + kk * 64 + ((lane >> 4) << 4)) ^ ((brow & 7) << 4);
        accS[n] = mfma16(aq, *reinterpret_cast<const s8v*>(kR + bad), accS[n]);
      }
    }
    __builtin_amdgcn_s_setprio(0);
    __syncthreads();           // kT reads (kstate) done before P overwrites
#pragma unroll
    for (int n = 0; n < 4; ++n)
#pragma unroll
      for (int r = 0; r < 4; ++r) {
        int i2 = wave * 16 + ((lane >> 4) << 2) + r;
        int j = n * 16 + (lane & 15);
        float v = (j <= i2) ? accS[n][r] : 0.f;
        int ad = ((i2 << 7) + (j << 1)) ^ ((i2 & 7) << 4);
        *reinterpret_cast<short*>(kT + ad) = (short)f2b(v);
      }
    __syncthreads();
    // PV: accO[i][d'] = sum_j P[i][j] v[j][d']
    __builtin_amdgcn_s_setprio(1);
#pragma unroll
    for (int kk = 0; kk < 2; ++kk) {
      int arow = wave * 16 + (lane & 15);
      int aad = ((arow << 7) + kk * 64 + ((lane >> 4) << 4)) ^ ((arow & 7) << 4);
      s8v ap = *reinterpret_cast<const s8v*>(kT + aad);
#pragma unroll
      for (int n = 0; n < 4; ++n) {
        int brow = n * 16 + (lane & 15);
        int bad = ((brow << 7) + kk * 64 + ((lane >> 4) << 4)) ^ ((brow & 7) << 4);
        accO[n] = mfma16(ap, *reinterpret_cast<const s8v*>(vTl + bad), accO[n]);
      }
    }
    __builtin_amdgcn_s_setprio(0);
  }
  wait_flag(&fS[bh], 32);                  // need all same-bh Sbuf

  // ---- S45: per-block Spre -> bf16 LDS; accO += q@Spre; aout --------------
  {
    char* LS = kR;             // kR dead since scores MFMA
    int srow = tid >> 2, scol0 = (tid & 3) * 16;
    const short* Sb = Sbuf + (size_t)bh * 32 * 4096 + srow * 64 + scol0;
    float acc0[8] = {}, acc1[8] = {};
#pragma unroll
    for (int c = 0; c < 32; ++c) {
      if (c < chunk) {
        s8v v0 = *reinterpret_cast<const s8v*>(Sb + (size_t)c * 4096);
        s8v v1 = *reinterpret_cast<const s8v*>(Sb + (size_t)c * 4096 + 8);
#pragma unroll
        for (int j = 0; j < 8; ++j) {
          acc0[j] += b2f((unsigned short)v0[j]);
          acc1[j] += b2f((unsigned short)v1[j]);
        }
      }
    }
    s8v o0, o1;
#pragma unroll
    for (int j = 0; j < 8; ++j) {
      o0[j] = (short)f2b(acc0[j]);
      o1[j] = (short)f2b(acc1[j]);
    }
    int byte0 = (srow << 7) + (scol0 << 1);
    int sw = (srow & 7) << 4;
    *reinterpret_cast<s8v*>(LS + ((byte0)      ^ sw)) = o0;
    *reinterpret_cast<s8v*>(LS + ((byte0 + 16) ^ sw)) = o1;
    __syncthreads();
    __builtin_amdgcn_s_setprio(1);
#pragma unroll
    for (int kk = 0; kk < 2; ++kk) {
      int arow = wave * 16 + (lane & 15);
      int aad = ((arow << 7) + kk * 64 + ((lane >> 4) << 4)) ^ ((arow & 7) << 4);
      s8v aq = *reinterpret_cast<const s8v*>(qL + aad);
#pragma unroll
      for (int n = 0; n < 4; ++n) {
        int brow = n * 16 + (lane & 15);
        int bad = ((brow << 7) + kk * 64 + ((lane >> 4) << 4)) ^ ((brow & 7) << 4);
        accO[n] = mfma16(aq, *reinterpret_cast<const s8v*>(LS + bad), accO[n]);
      }
    }
    __builtin_amdgcn_s_setprio(0);
#pragma unroll
    for (int n = 0; n < 4; ++n)
#pragma unroll
      for (int r = 0; r < 4; ++r) {
        int i2 = wave * 16 + ((lane >> 4) << 2) + r;
        int col = h * 64 + n * 16 + (lane & 15);
        size_t row = (size_t)b * 2048 + chunk * 64 + i2;
        aout[row * 512 + col] = (short)f2b(accO[n][r]);
      }
  }
  post_flag(&fA[g]);                       // aout rows (b,chunk) published

  // ---- S6: gemm1 (512 tiles of 64x64) ----
  {
    int xcd6 = bid & 7, rq = bid >> 3;
    int bx = rq & 7, by = xcd6 * 8 + (rq >> 3);
    wait_flag(&fA[by], 8);                 // all 8 heads of this row-chunk
    int m0 = by * 64, n0 = bx * 64;
    f32x4 a6[2][2] = {};
    gemm_core<64, 64, 2, 2>(aout, woT, arena, arena + 8192, m0, n0, tid, a6);
    int wr = (wave >> 1) * 32, wc = (wave & 1) * 32;
#pragma unroll
    for (int m = 0; m < 2; ++m)
#pragma unroll
      for (int n = 0; n < 2; ++n)
#pragma unroll
        for (int r = 0; r < 4; ++r) {
          int row = m0 + wr + m * 16 + ((lane >> 4) << 2) + r;
          int col = n0 + wc + n * 16 + (lane & 15);
          out[(size_t)row * 512 + col] = a6[m][n][r] + b_out[col];
        }
  }
}

// ---------------- fallback wrappers (R12 proven path) ------------------------
__global__ __launch_bounds__(256) void prep_k(const float* x, const float* gamma,
    short* xnb, const float* w_qkv, const float* w_a, const float* w_out,
    short* wT, short* woT) {
  __shared__ __align__(16) char arena[4224];
  st_prep(blockIdx.x, threadIdx.x, arena, x, gamma, xnb, w_qkv, w_a, w_out, wT, woT);
}
__global__ __launch_bounds__(256) void gemm0_k(const short* xnb, const short* wT,
    short* qkvb, const float* b_qkv, const float* b_a, float* araw, float* csum) {
  __shared__ __align__(16) char arena[24576];
  st_gemm0_fb(blockIdx.x, threadIdx.x, arena, xnb, wT, qkvb, b_qkv, b_a, araw, csum);
}
__global__ __launch_bounds__(256) void scan2_k(const short* qkvb, const float* araw,
    const float* csum, short* q2, short* k2, short* vT, short* Sbuf) {
  __shared__ __align__(16) char arena[32768];
  st_scan2(blockIdx.x, threadIdx.x, arena, qkvb, araw, csum, q2, k2, vT, Sbuf);
}
__global__ __launch_bounds__(256) void sprefix_k(const short* Sbuf, short* Spre) {
  st_sprefix(blockIdx.x, threadIdx.x, Sbuf, Spre);
}
__global__ __launch_bounds__(256) void attnk_k(const short* q2, const short* k2,
    const short* vT, const short* Spre, short* aout) {
  __shared__ __align__(16) char arena[32768];
  st_attnk(blockIdx.x, threadIdx.x, arena, q2, k2, vT, Spre, aout);
}
__global__ __launch_bounds__(256) void gemm1_k(const short* aout, const short* woT,
    float* out, const float* b_out) {
  __shared__ __align__(16) char arena[12288];
  st_gemm1_fb(blockIdx.x, threadIdx.x, arena, aout, woT, out, b_out);
}

// ---------------------------------------------------------------------------
extern "C" void kernel_launch(void* const* d_in, const int* in_sizes, int n_in,
                              void* d_out, int out_size, void* d_ws, size_t ws_size,
                              hipStream_t stream) {
  const float* x     = (const float*)d_in[0];
  const float* gamma = (const float*)d_in[1];
  const float* w_qkv = (const float*)d_in[2];
  const float* b_qkv = (const float*)d_in[3];
  const float* w_a   = (const float*)d_in[4];
  const float* b_a   = (const float*)d_in[5];
  const float* w_out = (const float*)d_in[6];
  const float* b_out = (const float*)d_in[7];
  float* out = (float*)d_out;
  char* ws = (char*)d_ws;

  const size_t MB = 1u << 20;
  short* xnb  = (short*)(ws);                 // 4 MiB   [4096][512] bf16
  short* wT   = (short*)(ws + 4  * MB);       // 2 MiB   [2048][512] bf16
  short* woT  = (short*)(ws + 6  * MB);       // 0.5 MiB [512][512]  bf16
  float* csum = (float*)(ws + 7  * MB);       // 128 KiB [16][32][64] f32
  short* Sbuf = (short*)(ws + 8  * MB);       // 4 MiB   [16][32][64][64] bf16
  short* aout = (short*)(ws + 12 * MB);       // 4 MiB   [4096][512] bf16
  // fallback-only buffers:
  short* qkvb = (short*)(ws + 16 * MB);       // 12 MiB
  float* araw = (float*)(ws + 28 * MB);       // 8 MiB
  short* Spre = (short*)(ws + 36 * MB);       // 4 MiB
  short* q2   = (short*)(ws + 40 * MB);       // 4 MiB
  short* k2   = (short*)(ws + 44 * MB);       // 4 MiB
  short* vT   = (short*)(ws + 48 * MB);       // 4 MiB
  int*   flags = (int*)(ws + 52 * MB);        // 96 ints (mega path only)

  int dev = 0; (void)hipGetDevice(&dev);
  int coop = 0;
  (void)hipDeviceGetAttribute(&coop, hipDeviceAttributeCooperativeLaunch, dev);
  int nb = 0;
  (void)hipOccupancyMaxActiveBlocksPerMultiprocessor(&nb, mega_k, 256, 0);

  hipError_t err = hipErrorUnknown;
  if (coop && nb >= 2) {
    void* args[] = {&x, &gamma, &w_qkv, &b_qkv, &w_a, &b_a, &w_out, &b_out,
                    &out, &xnb, &wT, &woT, &csum, &Sbuf, &aout, &flags};
    err = hipLaunchCooperativeKernel((void*)mega_k, dim3(512), dim3(256), args, 0, stream);
  }
  if (err != hipSuccess) {
    prep_k   <<<1792, 256, 0, stream>>>(x, gamma, xnb, w_qkv, w_a, w_out, wT, woT);
    gemm0_k  <<<1024, 256, 0, stream>>>(xnb, wT, qkvb, b_qkv, b_a, araw, csum);
    scan2_k  <<<512,  256, 0, stream>>>(qkvb, araw, csum, q2, k2, vT, Sbuf);
    sprefix_k<<<256,  256, 0, stream>>>(Sbuf, Spre);
    attnk_k  <<<512,  256, 0, stream>>>(q2, k2, vT, Spre, aout);
    gemm1_k  <<<1024, 256, 0, stream>>>(aout, woT, out, b_out);
  }
}